// Round 5
// baseline (89.750 us; speedup 1.0000x reference)
//
#include <hip/hip_runtime.h>
#include <math.h>

#define HH 300
#define WW 300
#define CC 4
#define MM 4096
#define KP 640          // padded K (fp8 bytes/row), 2*W=600 -> 640
#define NKC (KP/32)     // 20 k-chunks of 32 B
#define CSTRIDE 384     // per-coil row stride (3*128: every 128-row tile coil-pure)
#define MP (CC*CSTRIDE) // 1536
#define NP 8192         // 2*M (real | imag output columns)
#define NRB (MP/128)    // 12 row-blocks

// prep grid: one thread per 16-B output segment, stores fully linear+coalesced
#define PA_BLK 240      // A: 20 chunks * 1536 rows * 2 segs / 256 = 61440 threads
#define PB_BLK 1280     // B: 20 chunks * 8192 rows * 2 segs / 256 = 327680 threads
#define PZ_BLK 129      // zero Kacc (32768 f32) + counters (32 i32)

typedef __attribute__((ext_vector_type(4))) float f32x4;
typedef __attribute__((ext_vector_type(4))) int int4v;
typedef __attribute__((ext_vector_type(8))) int int8v;

#define TWO_PI 6.283185307179586f

// prep r5: segment-linear layout. Thread idx owns output bytes [idx*16, idx*16+16).
// For A: idx = (q*MP + row)*2 + s  <=>  cmaddr(MP, row, q*32 + s*16)  (bit-identical
// to the old chunk-major layout gemm reads). Waves store 1 KB contiguous dwordx4.
// Old prep issued 3.3M scattered 2-B stores (4x32-B segments 256KB apart per wave)
// -- suspected cause of the ~20us prep anomaly.
__global__ __launch_bounds__(256) void prep_kernel(
    const float* __restrict__ img, const float* __restrict__ csm,
    const float* __restrict__ omega, unsigned char* __restrict__ A,
    unsigned char* __restrict__ B, float* __restrict__ Kz,
    int* __restrict__ counters, float* __restrict__ out)
{
    const int bid = blockIdx.x;
    const int t   = threadIdx.x;
    if (bid == 0 && t == 0) out[0] = 0.0f;

    if (bid < PA_BLK) {
        // ---- A: sim = csm * img, fp8 e4m3, chunk-major ----
        const int idx = bid * 256 + t;        // 0..61439 = (q*MP+row)*2+s
        const int s   = idx & 1;
        const int rq  = idx >> 1;             // q*MP + row
        const int q   = rq / MP;
        const int row = rq - q * MP;
        const int c   = row / CSTRIDE;
        const int h   = row - c * CSTRIDE;
        const int k0  = q * 32 + s * 16;
        float v[16];
        if (h < HH) {
            #pragma unroll
            for (int e = 0; e < 16; ++e) {
                const int k = k0 + e;
                float val = 0.0f;
                if (k < 2 * WW) {
                    const int w = (k < WW) ? k : k - WW;
                    const float im = img[h * WW + w];
                    const float cs = csm[(((size_t)c * HH + h) * WW + w) * 2 + (k < WW ? 0 : 1)];
                    val = cs * im;
                }
                v[e] = val;
            }
        } else {
            #pragma unroll
            for (int e = 0; e < 16; ++e) v[e] = 0.0f;
        }
        int4v d;
        #pragma unroll
        for (int u = 0; u < 4; ++u) {
            int dw = __builtin_amdgcn_cvt_pk_fp8_f32(v[4*u],   v[4*u+1], 0,  false);
            dw     = __builtin_amdgcn_cvt_pk_fp8_f32(v[4*u+2], v[4*u+3], dw, true);
            d[u] = dw;
        }
        *(int4v*)(A + (size_t)idx * 16) = d;
    } else if (bid < PA_BLK + PB_BLK) {
        // ---- B^T: row m (real col) = [cos | sin | 0]; row m+MM (imag) = [-sin | cos | 0] ----
        const int idx = (bid - PA_BLK) * 256 + t;  // 0..327679 = (q*NP+row)*2+s
        const int s   = idx & 1;
        const int rq  = idx >> 1;                  // q*NP + row
        const int q   = rq >> 13;                  // NP = 8192
        const int row = rq & (NP - 1);
        const int m   = row & (MM - 1);
        const bool imag = row >= MM;
        const float om1 = omega[MM + m];
        const int k0  = q * 32 + s * 16;
        float v[16];
        #pragma unroll
        for (int e = 0; e < 16; ++e) {
            const int k = k0 + e;
            float val = 0.0f;
            if (k < 2 * WW) {
                const int w = (k < WW) ? k : k - WW;
                const float th = TWO_PI * om1 * (float)(w - 150);
                const float sn = __sinf(th), cs = __cosf(th);
                val = imag ? ((k < WW) ? -sn : cs)
                           : ((k < WW) ?  cs : sn);
            }
            v[e] = val;
        }
        int4v d;
        #pragma unroll
        for (int u = 0; u < 4; ++u) {
            int dw = __builtin_amdgcn_cvt_pk_fp8_f32(v[4*u],   v[4*u+1], 0,  false);
            dw     = __builtin_amdgcn_cvt_pk_fp8_f32(v[4*u+2], v[4*u+3], dw, true);
            d[u] = dw;
        }
        *(int4v*)(B + (size_t)idx * 16) = d;
    } else {
        const int idx = (bid - PA_BLK - PB_BLK) * 256 + t;  // 0..33023
        if (idx < 2 * CC * MM)           Kz[idx] = 0.0f;         // Kacc zero (128 KB)
        else if (idx < 2 * CC * MM + 32) counters[idx - 2 * CC * MM] = 0;
    }
}

// Barrier-free fp8 MX GEMM (identical to r4-verified): fragments global->VGPR
// (chunk-major, coalesced), 128x128 tiles, XCD-partitioned swizzle
// (r1: FETCH=compulsory-only). Fused fence-free loss tail: atomicAdd is
// device-scope on gfx950 [m20]; __syncthreads drains vmcnt(0) before s_barrier
// so each block's Kacc atomics are globally complete before t0 bumps the
// per-m-group counter; winner (24th contributor) reads Kacc via atomic RMWs.
__global__ __launch_bounds__(256) void gemm_kernel(
    const unsigned char* __restrict__ A, const unsigned char* __restrict__ B,
    const float* __restrict__ omega, const float* __restrict__ kdata,
    float* __restrict__ Kacc, int* __restrict__ counters,
    float* __restrict__ out)
{
    __shared__ float2 red[128];
    __shared__ int winner;
    __shared__ float lred[4];

    const int t    = threadIdx.x;
    const int wave = t >> 6;
    const int ln   = t & 63;

    // ---- XCD-aware remap: flat -> (col-block, row-block), bijective ----
    const int flat = blockIdx.x;        // 0..767, dispatch round-robins XCDs
    const int xcd  = flat & 7;
    const int q    = flat >> 3;         // 0..95 within this XCD
    const int cb   = xcd * 8 + (q & 7); // col-block 0..63 (8 per XCD)
    const int rowb = q >> 3;            // row-block 0..11
    const int row0 = rowb * 128;
    const int col0 = cb * 128;

    const int wr = wave >> 1, wc = wave & 1;
    const int lr = ln & 15;
    const int lq = ln >> 4;

    if (t < 128) red[t] = make_float2(0.0f, 0.0f);

    const int arow = row0 + wr * 64 + lr;   // base row for this lane's A frags
    const int bcol = col0 + wc * 64 + lr;   // base col for this lane's B frags

    f32x4 acc[4][4] = {};

    #pragma unroll
    for (int kc = 0; kc < NKC; kc += 4) {   // 5 fully-unrolled K-steps (K=128 each)
        int8v a[4], b[4];
        #pragma unroll
        for (int i = 0; i < 4; ++i) {
            const unsigned char* pA = A + ((size_t)(kc + lq) * MP + arow + i * 16) * 32;
            int4v lo = *(const int4v*)pA;
            int4v hi = *(const int4v*)(pA + 16);
            a[i] = __builtin_shufflevector(lo, hi, 0, 1, 2, 3, 4, 5, 6, 7);
        }
        #pragma unroll
        for (int j = 0; j < 4; ++j) {
            const unsigned char* pB = B + ((size_t)(kc + lq) * NP + bcol + j * 16) * 32;
            int4v lo = *(const int4v*)pB;
            int4v hi = *(const int4v*)(pB + 16);
            b[j] = __builtin_shufflevector(lo, hi, 0, 1, 2, 3, 4, 5, 6, 7);
        }
        #pragma unroll
        for (int i = 0; i < 4; ++i)
            #pragma unroll
            for (int j = 0; j < 4; ++j)
                acc[i][j] = __builtin_amdgcn_mfma_scale_f32_16x16x128_f8f6f4(
                    a[i], b[j], acc[i][j], 0, 0,      // cbsz=0 (fp8), blgp=0 (fp8)
                    0, 0x7f7f7f7f, 0, 0x7f7f7f7f);    // unit E8M0 scales
    }

    __syncthreads();   // red[] init visible before epilogue atomics

    // ---- fused stage-2 epilogue: red[col] = sum_h acc * ey(m,h) ----
    const int c  = row0 / CSTRIDE;   // block-uniform (CSTRIDE = 3*128)
    const int h0 = row0 - c * CSTRIDE;

    #pragma unroll
    for (int j = 0; j < 4; ++j) {
        const int jcol = wc * 64 + j * 16 + lr;
        const int m = (col0 + jcol) & (MM - 1);
        const float om0 = omega[m];
        const float th = TWO_PI * om0;
        const float ss = __sinf(th), sc = __cosf(th);
        const float str = sc, sti = -ss;               // step = exp(-2pi i om0)
        float s2r = str * str - sti * sti, s2i = 2.0f * str * sti;
        float s4r = s2r * s2r - s2i * s2i, s4i = 2.0f * s2r * s2i;
        float s8r = s4r * s4r - s4i * s4i, s8i = 2.0f * s4r * s4i;
        float s16r = s8r * s8r - s8i * s8i, s16i = 2.0f * s8r * s8i;

        const int hb0 = h0 + wr * 64 + lq * 4;
        const float thb = TWO_PI * om0 * (float)(hb0 - 150);
        const float sn = __sinf(thb), cs = __cosf(thb);
        float byr = cs, byi = -sn;                     // ey at h = hb0

        float pr = 0.0f, pi = 0.0f;
        #pragma unroll
        for (int i = 0; i < 4; ++i) {
            float er = byr, ei = byi;
            #pragma unroll
            for (int r = 0; r < 4; ++r) {
                const float v = acc[i][j][r];
                pr = fmaf(v, er, pr);
                pi = fmaf(v, ei, pi);
                float nr = er * str - ei * sti;
                ei = er * sti + ei * str;
                er = nr;
            }
            float nbr = byr * s16r - byi * s16i;       // advance base by 16 rows
            byi = byr * s16i + byi * s16r;
            byr = nbr;
        }
        pr += __shfl_down(pr, 32); pi += __shfl_down(pi, 32);
        pr += __shfl_down(pr, 16); pi += __shfl_down(pi, 16);
        if (lq == 0) {
            atomicAdd(&red[jcol].x, pr);
            atomicAdd(&red[jcol].y, pi);
        }
    }
    __syncthreads();

    // ---- accumulate into Kacc: k[c][m] = P_real + i * P_imag ----
    const int g = (col0 >> 7) & 31;      // m-group 0..31 (128 m's each)
    const bool realcol = (col0 < MM);
    if (t < 128) {
        const float2 p = red[t];
        const int m = (col0 + t) & (MM - 1);
        float* kc = Kacc + ((size_t)c * MM + m) * 2;
        if (realcol) {
            atomicAdd(kc,     p.x);
            atomicAdd(kc + 1, p.y);
        } else {
            atomicAdd(kc,    -p.y);
            atomicAdd(kc + 1,  p.x);
        }
    }
    // __syncthreads() emits s_waitcnt vmcnt(0) before s_barrier: this block's
    // device-scope Kacc atomics are globally complete before t0 bumps the counter.
    __syncthreads();
    if (t == 0) winner = (atomicAdd(&counters[g], 1) == 23) ? 1 : 0;  // 24 contributors
    __syncthreads();

    if (winner) {                        // block-uniform branch
        float val = 0.0f;
        #pragma unroll
        for (int u = 0; u < 2; ++u) {
            const int idx = u * 256 + t;        // 0..511 = 4 coils x 128 m's
            const int c2 = idx >> 7;
            const int m  = g * 128 + (idx & 127);
            float* kc = Kacc + ((size_t)c2 * MM + m) * 2;
            // coherent RMW reads (same path as the writes; cross-XCD safe)
            float kr = atomicAdd(kc,     0.0f) * (1.0f / 300.0f);
            float ki = atomicAdd(kc + 1, 0.0f) * (1.0f / 300.0f);
            const float om0 = omega[m];
            const float om1 = omega[MM + m];
            const size_t kidx = ((size_t)c2 * MM + m) * 2;
            const float kdr = kdata[kidx];
            const float kdi = kdata[kidx + 1];
            const float w0 = om0 * TWO_PI, w1 = om1 * TWO_PI;
            const float wg = sqrtf(w0 * w0 + w1 * w1) + 1.0f;
            const float dr = wg * (kr - kdr);
            const float di = wg * (ki - kdi);
            val += (dr * dr + di * di) * (1.0f / (2.0f * CC * MM));
        }
        #pragma unroll
        for (int off = 32; off > 0; off >>= 1) val += __shfl_down(val, off);
        if (ln == 0) lred[wave] = val;
        __syncthreads();
        if (t == 0) atomicAdd(out, lred[0] + lred[1] + lred[2] + lred[3]);
    }
}

extern "C" void kernel_launch(void* const* d_in, const int* in_sizes, int n_in,
                              void* d_out, int out_size, void* d_ws, size_t ws_size,
                              hipStream_t stream) {
    const float* img   = (const float*)d_in[0];   // (300,300,1)
    const float* kdata = (const float*)d_in[1];   // (1,4,4096,2)
    const float* omega = (const float*)d_in[2];   // (1,2,4096)
    const float* csm   = (const float*)d_in[4];   // (4,300,300,2)
    float* out = (float*)d_out;

    unsigned char* Aws = (unsigned char*)d_ws;                  // MP*KP  = 0.98 MB
    unsigned char* Bws = (unsigned char*)d_ws + (1u << 20);     // NP*KP  = 5.24 MB
    float* Kacc     = (float*)((char*)d_ws + (8u << 20));       // 4x4096 float2 = 128 KB
    int*   counters = (int*)((char*)d_ws + (8u << 20) + (256u << 10)); // 32 ints

    prep_kernel<<<PA_BLK + PB_BLK + PZ_BLK, 256, 0, stream>>>(
        img, csm, omega, Aws, Bws, Kacc, counters, out);
    gemm_kernel<<<(NP / 128) * NRB, 256, 0, stream>>>(
        Aws, Bws, omega, kdata, Kacc, counters, out);
}

// Round 6
// 88.830 us; speedup vs baseline: 1.0104x; 1.0104x over previous
//
#include <hip/hip_runtime.h>
#include <math.h>

#define HH 300
#define WW 300
#define CC 4
#define MM 4096
#define KP 640          // padded K (fp8 bytes/row), 2*W=600 -> 640
#define NKC (KP/32)     // 20 k-chunks of 32 B
#define CSTRIDE 384     // per-coil row stride (3*128: every 128-row tile coil-pure)
#define MP (CC*CSTRIDE) // 1536
#define NP 8192         // 2*M (real | imag output columns)
#define NRB (MP/128)    // 12 row-blocks

#define ABLK 1920       // prep blocks building A
#define BBLK 2560       // prep blocks building B
#define ZBLK 129        // prep blocks zeroing Kacc (32768 f32) + counters (32 i32)

typedef __attribute__((ext_vector_type(4))) float f32x4;
typedef __attribute__((ext_vector_type(4))) int int4v;
typedef __attribute__((ext_vector_type(8))) int int8v;

#define TWO_PI 6.283185307179586f

// Chunk-major element address: elem (row, k) of an R-row matrix lives at
// ((k/32)*R + row)*32 + (k%32).
__device__ __forceinline__ size_t cmaddr(int R, int row, int k) {
    return ((size_t)(k >> 5) * R + row) * 32 + (k & 31);
}

// A value at (row, k): row = c*CSTRIDE + h; k<300 -> sim_r[w=k]; 300<=k<600 -> sim_i; else 0
__device__ __forceinline__ float aval(const float* img, const float* csm,
                                      int c, int h, int k) {
    if (k >= 2 * WW) return 0.0f;
    int w = (k < WW) ? k : k - WW;
    float im = img[h * WW + w];
    const float* cs = csm + (((size_t)c * HH + h) * WW + w) * 2;
    return ((k < WW) ? cs[0] : cs[1]) * im;
}

// 32-byte fragment load (two dwordx4), chunk-major source
__device__ __forceinline__ int8v ld32(const unsigned char* __restrict__ p) {
    int4v lo = *(const int4v*)p;
    int4v hi = *(const int4v*)(p + 16);
    return __builtin_shufflevector(lo, hi, 0, 1, 2, 3, 4, 5, 6, 7);
}

// prep (r4-verified version): zero out[0]/Kacc/counters, build A (MP x KP fp8
// e4m3, chunk-major) and B^T (NP x KP fp8, chunk-major).
__global__ __launch_bounds__(256) void prep_kernel(
    const float* __restrict__ img, const float* __restrict__ csm,
    const float* __restrict__ omega, unsigned char* __restrict__ A,
    unsigned char* __restrict__ B, float* __restrict__ Kz,
    int* __restrict__ counters, float* __restrict__ out)
{
    const int bid = blockIdx.x;
    if (bid == 0 && threadIdx.x == 0) out[0] = 0.0f;
    if (bid < ABLK) {
        int idx = bid * 256 + threadIdx.x;            // pair index
        int row = idx / (KP / 2);
        int k   = (idx - row * (KP / 2)) * 2;
        int c = row / CSTRIDE;
        int h = row - c * CSTRIDE;
        float v0 = 0.0f, v1 = 0.0f;
        if (h < HH) { v0 = aval(img, csm, c, h, k); v1 = aval(img, csm, c, h, k + 1); }
        int pk = __builtin_amdgcn_cvt_pk_fp8_f32(v0, v1, 0, false);
        *(ushort*)(A + cmaddr(MP, row, k)) = (ushort)pk;   // k even: pair stays in chunk
    } else if (bid < ABLK + BBLK) {
        int idx = (bid - ABLK) * 256 + threadIdx.x;   // 0 .. 4096*160-1
        int m  = idx / 160;
        int wp = idx - m * 160;
        if (wp < 150) {
            int w = wp * 2;
            float om1 = omega[MM + m];
            float a0 = TWO_PI * om1 * (float)(w - 150);
            float a1 = TWO_PI * om1 * (float)(w - 149);
            float s0 = __sinf(a0), c0 = __cosf(a0);
            float s1 = __sinf(a1), c1 = __cosf(a1);
            // ez = exp(-i th): ez_r = cos, ez_i = -sin
            ushort rr = (ushort)__builtin_amdgcn_cvt_pk_fp8_f32(c0, c1, 0, false);
            ushort ii = (ushort)__builtin_amdgcn_cvt_pk_fp8_f32(-s0, -s1, 0, false);
            ushort ni = (ushort)__builtin_amdgcn_cvt_pk_fp8_f32(s0, s1, 0, false); // -ez_i
            *(ushort*)(B + cmaddr(NP, m,      w))        = rr;  // real col, ez_r
            *(ushort*)(B + cmaddr(NP, m,      WW + w))   = ni;  // real col, -ez_i
            *(ushort*)(B + cmaddr(NP, m + MM, w))        = ii;  // imag col, ez_i
            *(ushort*)(B + cmaddr(NP, m + MM, WW + w))   = rr;  // imag col, ez_r
        } else {
            int k = 600 + (wp - 150) * 4;             // 600..636, 4-B aligned in-chunk
            *(unsigned int*)(B + cmaddr(NP, m,      k)) = 0u;
            *(unsigned int*)(B + cmaddr(NP, m + MM, k)) = 0u;
        }
    } else {
        int idx = (bid - ABLK - BBLK) * 256 + threadIdx.x;  // 0..33023
        if (idx < 2 * CC * MM)           Kz[idx] = 0.0f;         // Kacc zero (128 KB)
        else if (idx < 2 * CC * MM + 32) counters[idx - 2 * CC * MM] = 0;
    }
}

// fp8 MX GEMM. r6 change: explicit 2-deep register double-buffer in the K-loop.
// r1 counters showed VGPR_Count=88 -> compiler allocated no prefetch depth; each
// K-step exposed full L2 latency (~400cy) vs 138cy of MFMA. Now step s+1's 8
// fragment loads are issued BEFORE step s's MFMA cluster (static buffer index,
// fully unrolled), pinned by sched_barrier(0) so the scheduler can't sink them.
// Everything else identical to r4-verified (XCD swizzle, fused fence-free loss).
__global__ __launch_bounds__(256) void gemm_kernel(
    const unsigned char* __restrict__ A, const unsigned char* __restrict__ B,
    const float* __restrict__ omega, const float* __restrict__ kdata,
    float* __restrict__ Kacc, int* __restrict__ counters,
    float* __restrict__ out)
{
    __shared__ float2 red[128];
    __shared__ int winner;
    __shared__ float lred[4];

    const int t    = threadIdx.x;
    const int wave = t >> 6;
    const int ln   = t & 63;

    // ---- XCD-aware remap: flat -> (col-block, row-block), bijective ----
    const int flat = blockIdx.x;        // 0..767, dispatch round-robins XCDs
    const int xcd  = flat & 7;
    const int q    = flat >> 3;         // 0..95 within this XCD
    const int cb   = xcd * 8 + (q & 7); // col-block 0..63 (8 per XCD)
    const int rowb = q >> 3;            // row-block 0..11
    const int row0 = rowb * 128;
    const int col0 = cb * 128;

    const int wr = wave >> 1, wc = wave & 1;
    const int lr = ln & 15;
    const int lq = ln >> 4;

    if (t < 128) red[t] = make_float2(0.0f, 0.0f);

    const int arow = row0 + wr * 64 + lr;   // base row for this lane's A frags
    const int bcol = col0 + wc * 64 + lr;   // base col for this lane's B frags

    const unsigned char* pAbase = A + ((size_t)lq * MP + arow) * 32;
    const unsigned char* pBbase = B + ((size_t)lq * NP + bcol) * 32;

    f32x4 acc[4][4] = {};
    int8v af[2][4], bf[2][4];

    // prologue: fragments for K-step 0 (chunks lq..lq+3 via kc=0)
    #pragma unroll
    for (int i = 0; i < 4; ++i) af[0][i] = ld32(pAbase + (size_t)i * (16 * 32));
    #pragma unroll
    for (int j = 0; j < 4; ++j) bf[0][j] = ld32(pBbase + (size_t)j * (16 * 32));

    #pragma unroll
    for (int s = 0; s < 5; ++s) {           // 5 K-steps of K=128 (4 chunks each)
        const int cur = s & 1;
        if (s < 4) {                        // prefetch step s+1 before MFMAs of s
            const size_t offA = (size_t)(s + 1) * 4 * MP * 32;
            const size_t offB = (size_t)(s + 1) * 4 * NP * 32;
            #pragma unroll
            for (int i = 0; i < 4; ++i)
                af[cur ^ 1][i] = ld32(pAbase + offA + (size_t)i * (16 * 32));
            #pragma unroll
            for (int j = 0; j < 4; ++j)
                bf[cur ^ 1][j] = ld32(pBbase + offB + (size_t)j * (16 * 32));
        }
        __builtin_amdgcn_sched_barrier(0);  // keep prefetch above the MFMA cluster
        #pragma unroll
        for (int i = 0; i < 4; ++i)
            #pragma unroll
            for (int j = 0; j < 4; ++j)
                acc[i][j] = __builtin_amdgcn_mfma_scale_f32_16x16x128_f8f6f4(
                    af[cur][i], bf[cur][j], acc[i][j], 0, 0,   // cbsz=0, blgp=0 (fp8)
                    0, 0x7f7f7f7f, 0, 0x7f7f7f7f);             // unit E8M0 scales
    }

    __syncthreads();   // red[] init visible before epilogue atomics

    // ---- fused stage-2 epilogue: red[col] = sum_h acc * ey(m,h) ----
    const int c  = row0 / CSTRIDE;   // block-uniform (CSTRIDE = 3*128)
    const int h0 = row0 - c * CSTRIDE;

    #pragma unroll
    for (int j = 0; j < 4; ++j) {
        const int jcol = wc * 64 + j * 16 + lr;
        const int m = (col0 + jcol) & (MM - 1);
        const float om0 = omega[m];
        const float th = TWO_PI * om0;
        const float ss = __sinf(th), sc = __cosf(th);
        const float str = sc, sti = -ss;               // step = exp(-2pi i om0)
        float s2r = str * str - sti * sti, s2i = 2.0f * str * sti;
        float s4r = s2r * s2r - s2i * s2i, s4i = 2.0f * s2r * s2i;
        float s8r = s4r * s4r - s4i * s4i, s8i = 2.0f * s4r * s4i;
        float s16r = s8r * s8r - s8i * s8i, s16i = 2.0f * s8r * s8i;

        const int hb0 = h0 + wr * 64 + lq * 4;
        const float thb = TWO_PI * om0 * (float)(hb0 - 150);
        const float sn = __sinf(thb), cs = __cosf(thb);
        float byr = cs, byi = -sn;                     // ey at h = hb0

        float pr = 0.0f, pi = 0.0f;
        #pragma unroll
        for (int i = 0; i < 4; ++i) {
            float er = byr, ei = byi;
            #pragma unroll
            for (int r = 0; r < 4; ++r) {
                const float v = acc[i][j][r];
                pr = fmaf(v, er, pr);
                pi = fmaf(v, ei, pi);
                float nr = er * str - ei * sti;
                ei = er * sti + ei * str;
                er = nr;
            }
            float nbr = byr * s16r - byi * s16i;       // advance base by 16 rows
            byi = byr * s16i + byi * s16r;
            byr = nbr;
        }
        pr += __shfl_down(pr, 32); pi += __shfl_down(pi, 32);
        pr += __shfl_down(pr, 16); pi += __shfl_down(pi, 16);
        if (lq == 0) {
            atomicAdd(&red[jcol].x, pr);
            atomicAdd(&red[jcol].y, pi);
        }
    }
    __syncthreads();

    // ---- accumulate into Kacc: k[c][m] = P_real + i * P_imag ----
    const int g = (col0 >> 7) & 31;      // m-group 0..31 (128 m's each)
    const bool realcol = (col0 < MM);
    if (t < 128) {
        const float2 p = red[t];
        const int m = (col0 + t) & (MM - 1);
        float* kc = Kacc + ((size_t)c * MM + m) * 2;
        if (realcol) {
            atomicAdd(kc,     p.x);
            atomicAdd(kc + 1, p.y);
        } else {
            atomicAdd(kc,    -p.y);
            atomicAdd(kc + 1,  p.x);
        }
    }
    // __syncthreads() emits s_waitcnt vmcnt(0) before s_barrier: this block's
    // device-scope Kacc atomics are globally complete before t0 bumps the counter.
    __syncthreads();
    if (t == 0) winner = (atomicAdd(&counters[g], 1) == 23) ? 1 : 0;  // 24 contributors
    __syncthreads();

    if (winner) {                        // block-uniform branch
        float val = 0.0f;
        #pragma unroll
        for (int u = 0; u < 2; ++u) {
            const int idx = u * 256 + t;        // 0..511 = 4 coils x 128 m's
            const int c2 = idx >> 7;
            const int m  = g * 128 + (idx & 127);
            float* kc = Kacc + ((size_t)c2 * MM + m) * 2;
            // coherent RMW reads (same path as the writes; cross-XCD safe)
            float kr = atomicAdd(kc,     0.0f) * (1.0f / 300.0f);
            float ki = atomicAdd(kc + 1, 0.0f) * (1.0f / 300.0f);
            const float om0 = omega[m];
            const float om1 = omega[MM + m];
            const size_t kidx = ((size_t)c2 * MM + m) * 2;
            const float kdr = kdata[kidx];
            const float kdi = kdata[kidx + 1];
            const float w0 = om0 * TWO_PI, w1 = om1 * TWO_PI;
            const float wg = sqrtf(w0 * w0 + w1 * w1) + 1.0f;
            const float dr = wg * (kr - kdr);
            const float di = wg * (ki - kdi);
            val += (dr * dr + di * di) * (1.0f / (2.0f * CC * MM));
        }
        #pragma unroll
        for (int off = 32; off > 0; off >>= 1) val += __shfl_down(val, off);
        if (ln == 0) lred[wave] = val;
        __syncthreads();
        if (t == 0) atomicAdd(out, lred[0] + lred[1] + lred[2] + lred[3]);
    }
}

extern "C" void kernel_launch(void* const* d_in, const int* in_sizes, int n_in,
                              void* d_out, int out_size, void* d_ws, size_t ws_size,
                              hipStream_t stream) {
    const float* img   = (const float*)d_in[0];   // (300,300,1)
    const float* kdata = (const float*)d_in[1];   // (1,4,4096,2)
    const float* omega = (const float*)d_in[2];   // (1,2,4096)
    const float* csm   = (const float*)d_in[4];   // (4,300,300,2)
    float* out = (float*)d_out;

    unsigned char* Aws = (unsigned char*)d_ws;                  // MP*KP  = 0.98 MB
    unsigned char* Bws = (unsigned char*)d_ws + (1u << 20);     // NP*KP  = 5.24 MB
    float* Kacc     = (float*)((char*)d_ws + (8u << 20));       // 4x4096 float2 = 128 KB
    int*   counters = (int*)((char*)d_ws + (8u << 20) + (256u << 10)); // 32 ints

    prep_kernel<<<ABLK + BBLK + ZBLK, 256, 0, stream>>>(
        img, csm, omega, Aws, Bws, Kacc, counters, out);
    gemm_kernel<<<(NP / 128) * NRB, 256, 0, stream>>>(
        Aws, Bws, omega, kdata, Kacc, counters, out);
}

// Round 8
// 87.880 us; speedup vs baseline: 1.0213x; 1.0108x over previous
//
#include <hip/hip_runtime.h>
#include <math.h>

#define HH 300
#define WW 300
#define CC 4
#define MM 4096
#define KP 640          // padded K (fp8 bytes/row), 2*W=600 -> 640
#define NKC (KP/32)     // 20 k-chunks of 32 B
#define CSTRIDE 384     // per-coil row stride (3*128: every 128-row tile coil-pure)
#define MP (CC*CSTRIDE) // 1536
#define NP 8192         // 2*M (real | imag output columns)
#define NRB (MP/128)    // 12 row-blocks

#define ABLK 1920       // prep blocks building A
#define BBLK 2560       // prep blocks building B
#define ZBLK 129        // prep blocks zeroing Kacc (32768 f32) + counters (32 i32)

typedef __attribute__((ext_vector_type(4))) float f32x4;
typedef __attribute__((ext_vector_type(4))) int int4v;
typedef __attribute__((ext_vector_type(8))) int int8v;

#define TWO_PI 6.283185307179586f

// Chunk-major element address: elem (row, k) of an R-row matrix lives at
// ((k/32)*R + row)*32 + (k%32).
__device__ __forceinline__ size_t cmaddr(int R, int row, int k) {
    return ((size_t)(k >> 5) * R + row) * 32 + (k & 31);
}

// A value at (row, k): row = c*CSTRIDE + h; k<300 -> sim_r[w=k]; 300<=k<600 -> sim_i; else 0
__device__ __forceinline__ float aval(const float* img, const float* csm,
                                      int c, int h, int k) {
    if (k >= 2 * WW) return 0.0f;
    int w = (k < WW) ? k : k - WW;
    float im = img[h * WW + w];
    const float* cs = csm + (((size_t)c * HH + h) * WW + w) * 2;
    return ((k < WW) ? cs[0] : cs[1]) * im;
}

// async global->LDS, 16 B per lane (dest must be wave-uniform base + lane*16)
__device__ __forceinline__ void glds16(const unsigned char* g, unsigned char* l) {
    __builtin_amdgcn_global_load_lds(
        (const __attribute__((address_space(1))) unsigned int*)g,
        (__attribute__((address_space(3))) unsigned int*)l, 16, 0, 0);
}

// prep (r4-verified): zero out[0]/Kacc/counters, build A (MP x KP fp8 e4m3,
// chunk-major) and B^T (NP x KP fp8, chunk-major).
__global__ __launch_bounds__(256) void prep_kernel(
    const float* __restrict__ img, const float* __restrict__ csm,
    const float* __restrict__ omega, unsigned char* __restrict__ A,
    unsigned char* __restrict__ B, float* __restrict__ Kz,
    int* __restrict__ counters, float* __restrict__ out)
{
    const int bid = blockIdx.x;
    if (bid == 0 && threadIdx.x == 0) out[0] = 0.0f;
    if (bid < ABLK) {
        int idx = bid * 256 + threadIdx.x;            // pair index
        int row = idx / (KP / 2);
        int k   = (idx - row * (KP / 2)) * 2;
        int c = row / CSTRIDE;
        int h = row - c * CSTRIDE;
        float v0 = 0.0f, v1 = 0.0f;
        if (h < HH) { v0 = aval(img, csm, c, h, k); v1 = aval(img, csm, c, h, k + 1); }
        int pk = __builtin_amdgcn_cvt_pk_fp8_f32(v0, v1, 0, false);
        *(ushort*)(A + cmaddr(MP, row, k)) = (ushort)pk;   // k even: pair stays in chunk
    } else if (bid < ABLK + BBLK) {
        int idx = (bid - ABLK) * 256 + threadIdx.x;   // 0 .. 4096*160-1
        int m  = idx / 160;
        int wp = idx - m * 160;
        if (wp < 150) {
            int w = wp * 2;
            float om1 = omega[MM + m];
            float a0 = TWO_PI * om1 * (float)(w - 150);
            float a1 = TWO_PI * om1 * (float)(w - 149);
            float s0 = __sinf(a0), c0 = __cosf(a0);
            float s1 = __sinf(a1), c1 = __cosf(a1);
            // ez = exp(-i th): ez_r = cos, ez_i = -sin
            ushort rr = (ushort)__builtin_amdgcn_cvt_pk_fp8_f32(c0, c1, 0, false);
            ushort ii = (ushort)__builtin_amdgcn_cvt_pk_fp8_f32(-s0, -s1, 0, false);
            ushort ni = (ushort)__builtin_amdgcn_cvt_pk_fp8_f32(s0, s1, 0, false); // -ez_i
            *(ushort*)(B + cmaddr(NP, m,      w))        = rr;  // real col, ez_r
            *(ushort*)(B + cmaddr(NP, m,      WW + w))   = ni;  // real col, -ez_i
            *(ushort*)(B + cmaddr(NP, m + MM, w))        = ii;  // imag col, ez_i
            *(ushort*)(B + cmaddr(NP, m + MM, WW + w))   = rr;  // imag col, ez_r
        } else {
            int k = 600 + (wp - 150) * 4;             // 600..636, 4-B aligned in-chunk
            *(unsigned int*)(B + cmaddr(NP, m,      k)) = 0u;
            *(unsigned int*)(B + cmaddr(NP, m + MM, k)) = 0u;
        }
    } else {
        int idx = (bid - ABLK - BBLK) * 256 + threadIdx.x;  // 0..33023
        if (idx < 2 * CC * MM)           Kz[idx] = 0.0f;         // Kacc zero (128 KB)
        else if (idx < 2 * CC * MM + 32) counters[idx - 2 * CC * MM] = 0;
    }
}

// fp8 MX GEMM, r7/r8: LDS-staged K-loop. Theory: fragments were read
// global->VGPR at 2x intra-block redundancy (waves duplicate A-rows / B-cols)
// = 251 MB of L2 traffic -> per-XCD L2-BW bound ~7-16 us (fits r3/r6 nulls).
// Each K-step (4 chunks, K=128) stages A(16KB)+B(16KB) into LDS ONCE via
// global_load_lds(16B) and all waves read fragments via ds_read_b128.
// LDS layout [chunk][row][2][16B] with half-swap swizzle (half ^= (row>>2)&1),
// applied on the global SOURCE address at stage time and on the read side
// (both-sides rule): strided b128 reads then tile all 32 banks at the 8-pass
// structural floor. Single 32 KB buffer -> 3 blocks/CU; cross-block TLP hides
// the stage stall (m114). Epilogue + fused fence-free loss tail = r4-verified.
__global__ __launch_bounds__(256) void gemm_kernel(
    const unsigned char* __restrict__ A, const unsigned char* __restrict__ B,
    const float* __restrict__ omega, const float* __restrict__ kdata,
    float* __restrict__ Kacc, int* __restrict__ counters,
    float* __restrict__ out)
{
    __shared__ unsigned char ldsA[4 * 128 * 32];   // 16 KB
    __shared__ unsigned char ldsB[4 * 128 * 32];   // 16 KB
    __shared__ float2 red[128];
    __shared__ int winner;
    __shared__ float lred[4];

    const int t    = threadIdx.x;
    const int wave = t >> 6;
    const int ln   = t & 63;

    // ---- XCD-aware remap: flat -> (col-block, row-block), bijective ----
    const int flat = blockIdx.x;        // 0..767, dispatch round-robins XCDs
    const int xcd  = flat & 7;
    const int q    = flat >> 3;         // 0..95 within this XCD
    const int cb   = xcd * 8 + (q & 7); // col-block 0..63 (8 per XCD)
    const int rowb = q >> 3;            // row-block 0..11
    const int row0 = rowb * 128;
    const int col0 = cb * 128;

    const int wr = wave >> 1, wc = wave & 1;
    const int lr = ln & 15;
    const int lq = ln >> 4;

    if (t < 128) red[t] = make_float2(0.0f, 0.0f);

    // staging decomposition: thread t owns 16-B segment (row sr, half t&1)
    const int sr   = t >> 1;                         // 0..127
    const int sh16 = ((t & 1) ^ ((sr >> 2) & 1)) * 16;  // swizzled source half
    const int h0   = (lr >> 2) & 1;                  // read-side swizzle select

    f32x4 acc[4][4] = {};

    for (int s = 0; s < 5; ++s) {       // 5 K-steps of K=128 (4 chunks each)
        if (s > 0) __syncthreads();     // all waves done reading previous step
        #pragma unroll
        for (int u = 0; u < 4; ++u) {   // chunk 4s+u -> LDS chunk slot u
            const unsigned char* gA =
                A + (((size_t)(4 * s + u) * MP + row0 + sr) << 5) + sh16;
            const unsigned char* gB =
                B + (((size_t)(4 * s + u) * NP + col0 + sr) << 5) + sh16;
            glds16(gA, ldsA + (u << 12) + (t << 4));
            glds16(gB, ldsB + (u << 12) + (t << 4));
        }
        __syncthreads();                // drains vmcnt(0): staged data visible

        int8v a[4], b[4];
        #pragma unroll
        for (int i = 0; i < 4; ++i) {
            const int r = wr * 64 + i * 16 + lr;
            const unsigned char* p = ldsA + (((lq << 7) + r) << 5);
            int4v lo = *(const int4v*)(p + (h0 << 4));        // logical half 0
            int4v hi = *(const int4v*)(p + ((h0 ^ 1) << 4));  // logical half 1
            a[i] = __builtin_shufflevector(lo, hi, 0, 1, 2, 3, 4, 5, 6, 7);
        }
        #pragma unroll
        for (int j = 0; j < 4; ++j) {
            const int r = wc * 64 + j * 16 + lr;
            const unsigned char* p = ldsB + (((lq << 7) + r) << 5);
            int4v lo = *(const int4v*)(p + (h0 << 4));
            int4v hi = *(const int4v*)(p + ((h0 ^ 1) << 4));
            b[j] = __builtin_shufflevector(lo, hi, 0, 1, 2, 3, 4, 5, 6, 7);
        }
        #pragma unroll
        for (int i = 0; i < 4; ++i)
            #pragma unroll
            for (int j = 0; j < 4; ++j)
                acc[i][j] = __builtin_amdgcn_mfma_scale_f32_16x16x128_f8f6f4(
                    a[i], b[j], acc[i][j], 0, 0,      // cbsz=0 (fp8), blgp=0 (fp8)
                    0, 0x7f7f7f7f, 0, 0x7f7f7f7f);    // unit E8M0 scales
    }

    // ---- fused stage-2 epilogue: red[col] = sum_h acc * ey(m,h) ----
    const int c  = row0 / CSTRIDE;   // block-uniform (CSTRIDE = 3*128)
    const int h0r = row0 - c * CSTRIDE;

    #pragma unroll
    for (int j = 0; j < 4; ++j) {
        const int jcol = wc * 64 + j * 16 + lr;
        const int m = (col0 + jcol) & (MM - 1);
        const float om0 = omega[m];
        const float th = TWO_PI * om0;
        const float ss = __sinf(th), sc = __cosf(th);
        const float str = sc, sti = -ss;               // step = exp(-2pi i om0)
        float s2r = str * str - sti * sti, s2i = 2.0f * str * sti;
        float s4r = s2r * s2r - s2i * s2i, s4i = 2.0f * s2r * s2i;
        float s8r = s4r * s4r - s4i * s4i, s8i = 2.0f * s4r * s4i;
        float s16r = s8r * s8r - s8i * s8i, s16i = 2.0f * s8r * s8i;

        const int hb0 = h0r + wr * 64 + lq * 4;
        const float thb = TWO_PI * om0 * (float)(hb0 - 150);
        const float sn = __sinf(thb), cs = __cosf(thb);
        float byr = cs, byi = -sn;                     // ey at h = hb0

        float pr = 0.0f, pi = 0.0f;
        #pragma unroll
        for (int i = 0; i < 4; ++i) {
            float er = byr, ei = byi;
            #pragma unroll
            for (int r = 0; r < 4; ++r) {
                const float v = acc[i][j][r];
                pr = fmaf(v, er, pr);
                pi = fmaf(v, ei, pi);
                float nr = er * str - ei * sti;
                ei = er * sti + ei * str;
                er = nr;
            }
            float nbr = byr * s16r - byi * s16i;       // advance base by 16 rows
            byi = byr * s16i + byi * s16r;
            byr = nbr;
        }
        pr += __shfl_down(pr, 32); pi += __shfl_down(pi, 32);
        pr += __shfl_down(pr, 16); pi += __shfl_down(pi, 16);
        if (lq == 0) {
            atomicAdd(&red[jcol].x, pr);
            atomicAdd(&red[jcol].y, pi);
        }
    }
    __syncthreads();

    // ---- accumulate into Kacc: k[c][m] = P_real + i * P_imag ----
    const int g = (col0 >> 7) & 31;      // m-group 0..31 (128 m's each)
    const bool realcol = (col0 < MM);
    if (t < 128) {
        const float2 p = red[t];
        const int m = (col0 + t) & (MM - 1);
        float* kc = Kacc + ((size_t)c * MM + m) * 2;
        if (realcol) {
            atomicAdd(kc,     p.x);
            atomicAdd(kc + 1, p.y);
        } else {
            atomicAdd(kc,    -p.y);
            atomicAdd(kc + 1,  p.x);
        }
    }
    // __syncthreads() emits s_waitcnt vmcnt(0) before s_barrier: this block's
    // device-scope Kacc atomics are globally complete before t0 bumps the counter.
    __syncthreads();
    if (t == 0) winner = (atomicAdd(&counters[g], 1) == 23) ? 1 : 0;  // 24 contributors
    __syncthreads();

    if (winner) {                        // block-uniform branch
        float val = 0.0f;
        #pragma unroll
        for (int u = 0; u < 2; ++u) {
            const int idx = u * 256 + t;        // 0..511 = 4 coils x 128 m's
            const int c2 = idx >> 7;
            const int m  = g * 128 + (idx & 127);
            float* kc = Kacc + ((size_t)c2 * MM + m) * 2;
            // coherent RMW reads (same path as the writes; cross-XCD safe)
            float kr = atomicAdd(kc,     0.0f) * (1.0f / 300.0f);
            float ki = atomicAdd(kc + 1, 0.0f) * (1.0f / 300.0f);
            const float om0 = omega[m];
            const float om1 = omega[MM + m];
            const size_t kidx = ((size_t)c2 * MM + m) * 2;
            const float kdr = kdata[kidx];
            const float kdi = kdata[kidx + 1];
            const float w0 = om0 * TWO_PI, w1 = om1 * TWO_PI;
            const float wg = sqrtf(w0 * w0 + w1 * w1) + 1.0f;
            const float dr = wg * (kr - kdr);
            const float di = wg * (ki - kdi);
            val += (dr * dr + di * di) * (1.0f / (2.0f * CC * MM));
        }
        #pragma unroll
        for (int off = 32; off > 0; off >>= 1) val += __shfl_down(val, off);
        if (ln == 0) lred[wave] = val;
        __syncthreads();
        if (t == 0) atomicAdd(out, lred[0] + lred[1] + lred[2] + lred[3]);
    }
}

extern "C" void kernel_launch(void* const* d_in, const int* in_sizes, int n_in,
                              void* d_out, int out_size, void* d_ws, size_t ws_size,
                              hipStream_t stream) {
    const float* img   = (const float*)d_in[0];   // (300,300,1)
    const float* kdata = (const float*)d_in[1];   // (1,4,4096,2)
    const float* omega = (const float*)d_in[2];   // (1,2,4096)
    const float* csm   = (const float*)d_in[4];   // (4,300,300,2)
    float* out = (float*)d_out;

    unsigned char* Aws = (unsigned char*)d_ws;                  // MP*KP  = 0.98 MB
    unsigned char* Bws = (unsigned char*)d_ws + (1u << 20);     // NP*KP  = 5.24 MB
    float* Kacc     = (float*)((char*)d_ws + (8u << 20));       // 4x4096 float2 = 128 KB
    int*   counters = (int*)((char*)d_ws + (8u << 20) + (256u << 10)); // 32 ints

    prep_kernel<<<ABLK + BBLK + ZBLK, 256, 0, stream>>>(
        img, csm, omega, Aws, Bws, Kacc, counters, out);
    gemm_kernel<<<(NP / 128) * NRB, 256, 0, stream>>>(
        Aws, Bws, omega, kdata, Kacc, counters, out);
}

// Round 9
// 84.407 us; speedup vs baseline: 1.0633x; 1.0411x over previous
//
#include <hip/hip_runtime.h>
#include <math.h>

#define HH 300
#define WW 300
#define CC 4
#define MM 4096
#define KP 640          // padded K (fp8 bytes/row), 2*W=600 -> 640
#define NKC (KP/32)     // 20 k-chunks of 32 B
#define CSTRIDE 384     // per-coil row stride (3*128: every 128-row tile coil-pure)
#define MP (CC*CSTRIDE) // 1536
#define NP 8192         // 2*M (real | imag output columns)
#define NRB (MP/128)    // 12 row-blocks

typedef __attribute__((ext_vector_type(4))) float f32x4;
typedef __attribute__((ext_vector_type(4))) int int4v;
typedef __attribute__((ext_vector_type(8))) int int8v;

#define TWO_PI 6.283185307179586f

// Chunk-major element address: elem (row, k) of an R-row matrix lives at
// ((k/32)*R + row)*32 + (k%32). Fragment loads (16 rows x 32 B per lq-group)
// are then 8 contiguous 128-B segments per wave -> fully coalesced.
__device__ __forceinline__ size_t cmaddr(int R, int row, int k) {
    return ((size_t)(k >> 5) * R + row) * 32 + (k & 31);
}

// A value at (row, k): row = c*CSTRIDE + h; k<300 -> sim_r[w=k]; 300<=k<600 -> sim_i; else 0
__device__ __forceinline__ float aval(const float* img, const float* csm,
                                      int c, int h, int k) {
    if (k >= 2 * WW) return 0.0f;
    int w = (k < WW) ? k : k - WW;
    float im = img[h * WW + w];
    const float* cs = csm + (((size_t)c * HH + h) * WW + w) * 2;
    return ((k < WW) ? cs[0] : cs[1]) * im;
}

// prep: zero out[0], build A (MP x KP fp8 e4m3, chunk-major) and B^T (NP x KP fp8,
// chunk-major). B row m (real col) = [ez_r | -ez_i | 0pad]; row m+4096 (imag col)
// = [ez_i | ez_r | 0pad]. One thread per w-pair computes sincos once, writes 4 spots.
__global__ __launch_bounds__(256) void prep_kernel(
    const float* __restrict__ img, const float* __restrict__ csm,
    const float* __restrict__ omega, unsigned char* __restrict__ A,
    unsigned char* __restrict__ B, float* __restrict__ out)
{
    const int bid = blockIdx.x;
    if (bid == 0 && threadIdx.x == 0) out[0] = 0.0f;
    const int ABLK = (MP * KP / 2) / 256;   // 1920
    if (bid < ABLK) {
        int idx = bid * 256 + threadIdx.x;            // pair index
        int row = idx / (KP / 2);
        int k   = (idx - row * (KP / 2)) * 2;
        int c = row / CSTRIDE;
        int h = row - c * CSTRIDE;
        float v0 = 0.0f, v1 = 0.0f;
        if (h < HH) { v0 = aval(img, csm, c, h, k); v1 = aval(img, csm, c, h, k + 1); }
        int pk = __builtin_amdgcn_cvt_pk_fp8_f32(v0, v1, 0, false);
        *(ushort*)(A + cmaddr(MP, row, k)) = (ushort)pk;   // k even: pair stays in chunk
    } else {
        int idx = (bid - ABLK) * 256 + threadIdx.x;   // 0 .. 4096*160-1
        int m  = idx / 160;
        int wp = idx - m * 160;
        if (wp < 150) {
            int w = wp * 2;
            float om1 = omega[MM + m];
            float s0, c0, s1, c1;
            __sincosf(TWO_PI * om1 * (float)(w - 150), &s0, &c0);
            __sincosf(TWO_PI * om1 * (float)(w - 149), &s1, &c1);
            // ez = exp(-i th): ez_r = cos, ez_i = -sin
            ushort rr = (ushort)__builtin_amdgcn_cvt_pk_fp8_f32(c0, c1, 0, false);
            ushort ii = (ushort)__builtin_amdgcn_cvt_pk_fp8_f32(-s0, -s1, 0, false);
            ushort ni = (ushort)__builtin_amdgcn_cvt_pk_fp8_f32(s0, s1, 0, false); // -ez_i
            *(ushort*)(B + cmaddr(NP, m,      w))        = rr;  // real col, ez_r
            *(ushort*)(B + cmaddr(NP, m,      WW + w))   = ni;  // real col, -ez_i
            *(ushort*)(B + cmaddr(NP, m + MM, w))        = ii;  // imag col, ez_i
            *(ushort*)(B + cmaddr(NP, m + MM, WW + w))   = rr;  // imag col, ez_r
        } else {
            int k = 600 + (wp - 150) * 4;             // 600..636, 4-B aligned in-chunk
            *(unsigned int*)(B + cmaddr(NP, m,      k)) = 0u;
            *(unsigned int*)(B + cmaddr(NP, m + MM, k)) = 0u;
        }
    }
}

// Barrier-free fp8 MX GEMM: fragments loaded global->VGPR directly (chunk-major,
// coalesced), no LDS staging, no __syncthreads in the K-loop. Fused ey-rotation
// epilogue with one barrier pair at the end.
__global__ __launch_bounds__(256) void gemm_kernel(
    const unsigned char* __restrict__ A, const unsigned char* __restrict__ B,
    const float* __restrict__ omega, float2* __restrict__ P)
{
    __shared__ float2 red[128];

    const int t    = threadIdx.x;
    const int wave = t >> 6;
    const int ln   = t & 63;
    const int row0 = blockIdx.y * 128;
    const int col0 = blockIdx.x * 128;
    const int wr = wave >> 1, wc = wave & 1;
    const int lr = ln & 15;
    const int lq = ln >> 4;

    if (t < 128) red[t] = make_float2(0.0f, 0.0f);

    const int arow = row0 + wr * 64 + lr;   // base row for this lane's A frags
    const int bcol = col0 + wc * 64 + lr;   // base col for this lane's B frags

    f32x4 acc[4][4] = {};

    #pragma unroll
    for (int kc = 0; kc < NKC; kc += 4) {   // 5 fully-unrolled K-steps (K=128 each)
        int8v a[4], b[4];
        #pragma unroll
        for (int i = 0; i < 4; ++i) {
            const unsigned char* pA = A + ((size_t)(kc + lq) * MP + arow + i * 16) * 32;
            int4v lo = *(const int4v*)pA;
            int4v hi = *(const int4v*)(pA + 16);
            a[i] = __builtin_shufflevector(lo, hi, 0, 1, 2, 3, 4, 5, 6, 7);
        }
        #pragma unroll
        for (int j = 0; j < 4; ++j) {
            const unsigned char* pB = B + ((size_t)(kc + lq) * NP + bcol + j * 16) * 32;
            int4v lo = *(const int4v*)pB;
            int4v hi = *(const int4v*)(pB + 16);
            b[j] = __builtin_shufflevector(lo, hi, 0, 1, 2, 3, 4, 5, 6, 7);
        }
        #pragma unroll
        for (int i = 0; i < 4; ++i)
            #pragma unroll
            for (int j = 0; j < 4; ++j)
                acc[i][j] = __builtin_amdgcn_mfma_scale_f32_16x16x128_f8f6f4(
                    a[i], b[j], acc[i][j], 0, 0,      // cbsz=0 (fp8), blgp=0 (fp8)
                    0, 0x7f7f7f7f, 0, 0x7f7f7f7f);    // unit E8M0 scales
    }

    __syncthreads();   // red[] init visible before epilogue atomics

    // ---- fused stage-2 epilogue: P[rb][col] = sum_h acc * ey(m,h) ----
    const int c  = row0 / CSTRIDE;   // block-uniform (CSTRIDE = 3*128)
    const int h0 = row0 - c * CSTRIDE;

    #pragma unroll
    for (int j = 0; j < 4; ++j) {
        const int jcol = wc * 64 + j * 16 + lr;
        const int m = (col0 + jcol) & (MM - 1);
        const float om0 = omega[m];
        float ss, sc;
        __sincosf(TWO_PI * om0, &ss, &sc);
        const float str = sc, sti = -ss;               // step = exp(-2pi i om0)
        float s2r = str * str - sti * sti, s2i = 2.0f * str * sti;
        float s4r = s2r * s2r - s2i * s2i, s4i = 2.0f * s2r * s2i;
        float s8r = s4r * s4r - s4i * s4i, s8i = 2.0f * s4r * s4i;
        float s16r = s8r * s8r - s8i * s8i, s16i = 2.0f * s8r * s8i;

        const int hb0 = h0 + wr * 64 + lq * 4;
        float sn, cs;
        __sincosf(TWO_PI * om0 * (float)(hb0 - 150), &sn, &cs);
        float byr = cs, byi = -sn;                     // ey at h = hb0

        float pr = 0.0f, pi = 0.0f;
        #pragma unroll
        for (int i = 0; i < 4; ++i) {
            float er = byr, ei = byi;
            #pragma unroll
            for (int r = 0; r < 4; ++r) {
                const float v = acc[i][j][r];
                pr = fmaf(v, er, pr);
                pi = fmaf(v, ei, pi);
                float nr = er * str - ei * sti;
                ei = er * sti + ei * str;
                er = nr;
            }
            float nbr = byr * s16r - byi * s16i;       // advance base by 16 rows
            byi = byr * s16i + byi * s16r;
            byr = nbr;
        }
        pr += __shfl_down(pr, 32); pi += __shfl_down(pi, 32);
        pr += __shfl_down(pr, 16); pi += __shfl_down(pi, 16);
        if (lq == 0) {
            atomicAdd(&red[jcol].x, pr);
            atomicAdd(&red[jcol].y, pi);
        }
    }
    __syncthreads();

    if (t < 128) {
        const int rb = row0 >> 7;
        P[(size_t)rb * NP + col0 + t] = red[t];
    }
}

// loss: k[c,m] from 3 row-block partials. 256 blocks x 64 threads (one wave each).
__global__ __launch_bounds__(64) void loss_kernel(
    const float2* __restrict__ P, const float* __restrict__ kdata,
    const float* __restrict__ omega, float* __restrict__ out)
{
    const int t = blockIdx.x * 64 + threadIdx.x;   // 0..16383
    const int c = t >> 12;
    const int m = t & (MM - 1);

    float kr = 0.0f, ki = 0.0f;
    #pragma unroll
    for (int q = 0; q < 3; ++q) {
        const int rb = 3 * c + q;
        float2 p0 = P[(size_t)rb * NP + m];          // real-col partial
        float2 p1 = P[(size_t)rb * NP + m + MM];     // imag-col partial
        kr += p0.x - p1.y;
        ki += p0.y + p1.x;
    }
    kr *= (1.0f / 300.0f);
    ki *= (1.0f / 300.0f);

    const float om0 = omega[m];
    const float om1 = omega[MM + m];
    const size_t kidx = ((size_t)c * MM + m) * 2;
    const float kdr = kdata[kidx];
    const float kdi = kdata[kidx + 1];
    const float w0 = om0 * TWO_PI, w1 = om1 * TWO_PI;
    const float wg = sqrtf(w0 * w0 + w1 * w1) + 1.0f;
    const float dr = wg * (kr - kdr);
    const float di = wg * (ki - kdi);
    float val = (dr * dr + di * di) * (1.0f / (2.0f * CC * MM));

    #pragma unroll
    for (int off = 32; off > 0; off >>= 1) val += __shfl_down(val, off);
    if (threadIdx.x == 0) atomicAdd(out, val);
}

extern "C" void kernel_launch(void* const* d_in, const int* in_sizes, int n_in,
                              void* d_out, int out_size, void* d_ws, size_t ws_size,
                              hipStream_t stream) {
    const float* img   = (const float*)d_in[0];   // (300,300,1)
    const float* kdata = (const float*)d_in[1];   // (1,4,4096,2)
    const float* omega = (const float*)d_in[2];   // (1,2,4096)
    const float* csm   = (const float*)d_in[4];   // (4,300,300,2)
    float* out = (float*)d_out;

    unsigned char* Aws = (unsigned char*)d_ws;                  // MP*KP  = 0.98 MB
    unsigned char* Bws = (unsigned char*)d_ws + (1u << 20);     // NP*KP  = 5.24 MB
    float2*        Pws = (float2*)((char*)d_ws + (8u << 20));   // NRB*NP*8 = 786 KB

    const int ablk = (MP * KP / 2) / 256;      // 1920
    const int bblk = (MM * 160) / 256;         // 2560
    prep_kernel<<<ablk + bblk, 256, 0, stream>>>(img, csm, omega, Aws, Bws, out);
    gemm_kernel<<<dim3(NP / 128, MP / 128), 256, 0, stream>>>(Aws, Bws, omega, Pws);
    loss_kernel<<<CC * MM / 64, 64, 0, stream>>>(Pws, kdata, omega, out);
}